// Round 1
// baseline (2309.889 us; speedup 1.0000x reference)
//
#include <hip/hip_runtime.h>
#include <hip/hip_bf16.h>

#define NTHREADS 1024
#define RPB      64      // rows per block: 16384 / 256 blocks
#define DIN      64
#define DOUT     256
#define NSTEPS   100
#define PITERS   50
#define LAMBDAV  0.1f
#define YSTRIDE  260     // 256 + 4 pad (bank spread, keeps 16B alignment)
#define RSTRIDE  68      // 64 + 4 pad

__device__ __forceinline__ int swz(int j) { return ((j >> 4) & 7) << 2; }

__global__ __launch_bounds__(NTHREADS, 4)
void fista_persist(const float* __restrict__ inp,
                   const float* __restrict__ Wg,
                   const float* __restrict__ X0,
                   float* __restrict__ out)
{
    // 64KB + 65KB + 17KB + eps = ~146KB LDS -> 1 block/CU, 16 waves (4/SIMD)
    __shared__ float Wl[DOUT * DIN];      // XOR-swizzled: word j*64 + (k ^ swz(j))
    __shared__ float Yl[RPB * YSTRIDE];   // y iterate
    __shared__ float Rl[RPB * RSTRIDE];   // residual R = yW - in; also power-iter scratch
    __shared__ float scal[2];             // invL, thr

    const int tid = threadIdx.x;
    const int rb  = blockIdx.x * RPB;

    // ---- stage W into LDS (swizzled) ----
    #pragma unroll
    for (int i = 0; i < 4; ++i) {
        int gw = (tid + i * NTHREADS) * 4;     // word index, 16B aligned
        int j  = gw >> 6;
        int k0 = gw & 63;
        float4 w = *(const float4*)&Wg[gw];
        *(float4*)&Wl[j * DIN + (k0 ^ swz(j))] = w;
    }

    // ---- phase-1 mapping: thread -> (row p1r, cols p1k..p1k+3) of R ----
    const int p1r = tid >> 4;          // 0..63
    const int p1k = (tid & 15) << 2;   // 0,4,...,60
    const float4 in4 = *(const float4*)&inp[(size_t)(rb + p1r) * DIN + p1k];

    // ---- phase-2 mapping: thread -> rows rg*4..+3, cols jg*4..+3 of X ----
    const int rg  = tid >> 6;          // 0..15 (one wave per rg)
    const int jg  = tid & 63;          // 0..63
    const int sw2 = ((jg >> 2) & 7) << 2;   // swz(jg*4+jj), same for jj=0..3

    float X[4][4];
    #pragma unroll
    for (int rr = 0; rr < 4; ++rr) {
        float4 x = *(const float4*)&X0[(size_t)(rb + rg * 4 + rr) * DOUT + jg * 4];
        X[rr][0] = x.x; X[rr][1] = x.y; X[rr][2] = x.z; X[rr][3] = x.w;
        *(float4*)&Yl[(rg * 4 + rr) * YSTRIDE + jg * 4] = x;   // y0 = X0
    }
    __syncthreads();

    // ---- Lipschitz constant: 50 power iterations of Q = 2 W W^T (per-block redundant) ----
    {
        float* v   = Rl;         // 256
        float* u   = Rl + 256;   // 64
        float* red = Rl + 320;   // small
        if (tid < 256) v[tid] = 0.0625f;   // ones/sqrt(256)
        __syncthreads();
        for (int it = 0; it <= PITERS; ++it) {
            if (tid < 64) {                       // u = W^T v
                float s = 0.f;
                #pragma unroll 4
                for (int j = 0; j < 256; j += 4) {
                    float4 v4 = *(const float4*)&v[j];
                    s += v4.x * Wl[(j + 0) * DIN + (tid ^ swz(j + 0))];
                    s += v4.y * Wl[(j + 1) * DIN + (tid ^ swz(j + 1))];
                    s += v4.z * Wl[(j + 2) * DIN + (tid ^ swz(j + 2))];
                    s += v4.w * Wl[(j + 3) * DIN + (tid ^ swz(j + 3))];
                }
                u[tid] = s;
            }
            __syncthreads();
            float w2 = 0.f, contrib = 0.f;
            if (tid < 256) {                      // w2 = (Q v)[tid] = 2 * W[tid,:] . u
                float s = 0.f;
                const int sw = swz(tid);
                #pragma unroll
                for (int k = 0; k < 64; k += 4) {
                    float4 wv = *(const float4*)&Wl[tid * DIN + (k ^ sw)];
                    float4 u4 = *(const float4*)&u[k];
                    s += wv.x * u4.x + wv.y * u4.y + wv.z * u4.z + wv.w * u4.w;
                }
                w2 = 2.f * s;
                contrib = (it == PITERS) ? v[tid] * w2 : w2 * w2;  // Rayleigh vs norm^2
            }
            __syncthreads();
            if (it < PITERS && tid < 256) v[tid] = w2;
            float sq = (tid < 256) ? contrib : 0.f;
            #pragma unroll
            for (int off = 32; off >= 1; off >>= 1) sq += __shfl_down(sq, off);
            if (tid < 256 && (tid & 63) == 0) red[tid >> 6] = sq;
            __syncthreads();
            if (tid == 0) {
                float tot = red[0] + red[1] + red[2] + red[3];
                if (it < PITERS) red[8] = 1.f / sqrtf(tot);
                else { scal[0] = 1.f / tot; scal[1] = LAMBDAV / tot; }
            }
            __syncthreads();
            if (it < PITERS && tid < 256) v[tid] *= red[8];
            __syncthreads();
        }
    }

    const float invL = scal[0];
    const float thr  = scal[1];
    const float c2   = 2.f * invL;
    __syncthreads();

    // ---- 100 FISTA steps, all state resident (X regs, y LDS) ----
    float t = 1.f;
    for (int step = 0; step < NSTEPS; ++step) {
        // phase 1: R[p1r][p1k..+3] = y[p1r,:] @ W - in
        float4 acc = make_float4(-in4.x, -in4.y, -in4.z, -in4.w);
        {
            const float* yrow = &Yl[p1r * YSTRIDE];
            #pragma unroll 2
            for (int m = 0; m < 16; ++m) {        // 16-row groups share one swizzle
                const float* wp = &Wl[(m * 16) * DIN + (p1k ^ ((m & 7) << 2))];
                const float* yp = &yrow[m * 16];
                #pragma unroll
                for (int jj = 0; jj < 16; jj += 4) {
                    float4 yv  = *(const float4*)&yp[jj];
                    float4 w0  = *(const float4*)&wp[(jj + 0) * DIN];
                    float4 w1  = *(const float4*)&wp[(jj + 1) * DIN];
                    float4 w2v = *(const float4*)&wp[(jj + 2) * DIN];
                    float4 w3  = *(const float4*)&wp[(jj + 3) * DIN];
                    acc.x += yv.x * w0.x + yv.y * w1.x + yv.z * w2v.x + yv.w * w3.x;
                    acc.y += yv.x * w0.y + yv.y * w1.y + yv.z * w2v.y + yv.w * w3.y;
                    acc.z += yv.x * w0.z + yv.y * w1.z + yv.z * w2v.z + yv.w * w3.z;
                    acc.w += yv.x * w0.w + yv.y * w1.w + yv.z * w2v.w + yv.w * w3.w;
                }
            }
        }
        *(float4*)&Rl[p1r * RSTRIDE + p1k] = acc;
        __syncthreads();

        // phase 2: g = R @ W^T on the [4r x 4j] tile this thread owns
        float g[4][4];
        #pragma unroll
        for (int rr = 0; rr < 4; ++rr)
            #pragma unroll
            for (int jj = 0; jj < 4; ++jj) g[rr][jj] = 0.f;
        {
            const float* rp[4];
            const float* wq[4];
            #pragma unroll
            for (int rr = 0; rr < 4; ++rr) rp[rr] = &Rl[(rg * 4 + rr) * RSTRIDE];
            #pragma unroll
            for (int jj = 0; jj < 4; ++jj) wq[jj] = &Wl[(jg * 4 + jj) * DIN];
            #pragma unroll 2
            for (int kc = 0; kc < 64; kc += 4) {
                const int kx = kc ^ sw2;           // physical offset in swizzled W row
                float4 rv[4], wv[4];
                #pragma unroll
                for (int rr = 0; rr < 4; ++rr) rv[rr] = *(const float4*)&rp[rr][kc];
                #pragma unroll
                for (int jj = 0; jj < 4; ++jj) wv[jj] = *(const float4*)&wq[jj][kx];
                #pragma unroll
                for (int rr = 0; rr < 4; ++rr)
                    #pragma unroll
                    for (int jj = 0; jj < 4; ++jj)
                        g[rr][jj] += rv[rr].x * wv[jj].x + rv[rr].y * wv[jj].y
                                   + rv[rr].z * wv[jj].z + rv[rr].w * wv[jj].w;
            }
        }

        const float t2  = 0.5f + 0.5f * sqrtf(1.f + 4.f * t * t);
        const float mom = (t - 1.f) / t2;
        t = t2;

        #pragma unroll
        for (int rr = 0; rr < 4; ++rr) {
            float* yp = &Yl[(rg * 4 + rr) * YSTRIDE + jg * 4];
            float4 yv = *(const float4*)yp;
            float ya[4] = { yv.x, yv.y, yv.z, yv.w };
            float yn[4];
            #pragma unroll
            for (int jj = 0; jj < 4; ++jj) {
                float uu = ya[jj] - c2 * g[rr][jj];               // y - invL*grad
                float x2 = fmaxf(uu - thr, 0.f) + fminf(uu + thr, 0.f);  // prox
                yn[jj]   = x2 + mom * (x2 - X[rr][jj]);           // uses old X
                X[rr][jj] = x2;
            }
            *(float4*)yp = make_float4(yn[0], yn[1], yn[2], yn[3]);
        }
        __syncthreads();
    }

    // ---- store X ----
    #pragma unroll
    for (int rr = 0; rr < 4; ++rr) {
        *(float4*)&out[(size_t)(rb + rg * 4 + rr) * DOUT + jg * 4] =
            make_float4(X[rr][0], X[rr][1], X[rr][2], X[rr][3]);
    }
}

extern "C" void kernel_launch(void* const* d_in, const int* in_sizes, int n_in,
                              void* d_out, int out_size, void* d_ws, size_t ws_size,
                              hipStream_t stream) {
    (void)in_sizes; (void)n_in; (void)d_ws; (void)ws_size; (void)out_size;
    const float* inp = (const float*)d_in[0];   // [16384, 64]
    const float* Wg  = (const float*)d_in[1];   // [256, 64]
    const float* X0  = (const float*)d_in[2];   // [16384, 256]
    float* outp      = (float*)d_out;           // [16384, 256]
    fista_persist<<<16384 / RPB, NTHREADS, 0, stream>>>(inp, Wg, X0, outp);
}

// Round 2
// 566.118 us; speedup vs baseline: 4.0802x; 4.0802x over previous
//
#include <hip/hip_runtime.h>
#include <hip/hip_bf16.h>

#define NTH     512
#define RPB     64
#define DIN     64
#define DOUT    256
#define NSTEPS  100
#define PITERS  50
#define LAMBDAV 0.1f

typedef __bf16 bf16x8 __attribute__((ext_vector_type(8)));
typedef float  f32x4  __attribute__((ext_vector_type(4)));

__device__ __forceinline__ unsigned short f2bf(float x) {
    unsigned int u = __builtin_bit_cast(unsigned int, x);
    unsigned int r = (u + 0x7FFFu + ((u >> 16) & 1u)) >> 16;   // RNE
    return (unsigned short)r;
}
__device__ __forceinline__ float bf2f(unsigned short h) {
    unsigned int u = ((unsigned int)h) << 16;
    return __builtin_bit_cast(float, u);
}

// LDS byte layout (all per-lane-row reads XOR-swizzled with ((row&7)<<4)):
//   yh [64][256] bf16 @ 0       (row stride 512B)   yl @ 32768
//   Wh2[256][64] bf16 @ 65536   (row stride 128B)   Wl2 @ 98304
//   Rh [64][64]  bf16 @ 131072  (row stride 128B)   Rl @ 139264
//   fp32 W staging [256][64] (row stride 256B, same swizzle) overlays yh/yl.

__global__ __launch_bounds__(NTH, 2)
void fista_mfma(const float* __restrict__ inp,
                const float* __restrict__ Wg,
                const float* __restrict__ X0,
                float* __restrict__ out)
{
    __shared__ __align__(16) char lds[147456];
    __shared__ __align__(16) float vf[256];
    __shared__ __align__(16) float up[256];
    __shared__ __align__(16) float uf[64];
    __shared__ float red[16];
    __shared__ float scal[2];

    char* const yhb = lds;
    char* const ylb = lds + 32768;
    char* const whb = lds + 65536;
    char* const wlb = lds + 98304;
    char* const rhb = lds + 131072;
    char* const rlb = lds + 139264;
    char* const wst = lds;            // fp32 staging overlay

    const int tid  = threadIdx.x;
    const int w    = tid >> 6;
    const int lane = tid & 63;
    const int l4   = lane >> 4;       // 0..3
    const int ln   = lane & 15;       // 0..15
    const int rb   = blockIdx.x * RPB;

    // phase-1 tile assignment: wave -> n-tile nw, m-tiles {mw0, mw0+1}
    const int nw  = w & 3;
    const int mw0 = (w >> 2) * 2;
    // phase-2 tile assignment: wave -> m-tile mt2, n-tiles ng0..ng0+7
    const int mt2 = w >> 1;
    const int ng0 = (w & 1) * 8;

    // ---- stage W fp32 into LDS (swizzled), build Wh2/Wl2 bf16 hi/lo ----
    #pragma unroll
    for (int i = 0; i < 8; ++i) {
        int wi = (tid + i * NTH) * 4;          // flat word index into [256][64]
        int j = wi >> 6, k = wi & 63;
        f32x4 v = *(const f32x4*)&Wg[wi];
        *(f32x4*)(wst + j * 256 + ((k * 4) ^ ((j & 7) << 4))) = v;
    }
    for (int i = tid; i < DOUT * DIN; i += NTH) {
        int j = i >> 6, k = i & 63;
        float wv = Wg[i];
        unsigned short h = f2bf(wv);
        int off = j * 128 + ((k * 2) ^ ((j & 7) << 4));
        *(unsigned short*)(whb + off) = h;
        *(unsigned short*)(wlb + off) = f2bf(wv - bf2f(h));
    }

    // ---- per-thread constants from global (registers) ----
    float nin[2][4];                           // -in, phase-1 D layout
    #pragma unroll
    for (int s = 0; s < 2; ++s)
        #pragma unroll
        for (int r = 0; r < 4; ++r)
            nin[s][r] = -inp[(size_t)(rb + (mw0 + s) * 16 + l4 * 4 + r) * DIN + nw * 16 + ln];

    float xm[8][4], ym[8][4];                  // X, y masters, phase-2 D layout
    #pragma unroll
    for (int t8 = 0; t8 < 8; ++t8)
        #pragma unroll
        for (int r = 0; r < 4; ++r) {
            float v = X0[(size_t)(rb + mt2 * 16 + l4 * 4 + r) * DOUT + (ng0 + t8) * 16 + ln];
            xm[t8][r] = v; ym[t8][r] = v;
        }

    if (tid < 256) vf[tid] = 0.0625f;          // ones/sqrt(256)
    __syncthreads();

    // ---- Lipschitz: 50 power iterations of Q = 2 W W^T ----
    for (int it = 0; it <= PITERS; ++it) {
        if (tid < 256) {                       // partial u = W^T v (4-way j split)
            int col = tid & 63, jq = tid >> 6;
            float s = 0.f;
            #pragma unroll 4
            for (int j = jq * 64; j < jq * 64 + 64; ++j)
                s += vf[j] * *(const float*)(wst + j * 256 + ((col * 4) ^ ((j & 7) << 4)));
            up[tid] = s;
        }
        __syncthreads();
        if (tid < 64) uf[tid] = up[tid] + up[tid + 64] + up[tid + 128] + up[tid + 192];
        __syncthreads();
        float w2 = 0.f;
        if (tid < 256) {                       // w2 = 2 * W[tid,:] . u
            float s = 0.f;
            #pragma unroll
            for (int kc = 0; kc < 64; kc += 4) {
                f32x4 wv = *(const f32x4*)(wst + tid * 256 + ((kc * 4) ^ ((tid & 7) << 4)));
                f32x4 u4 = *(const f32x4*)&uf[kc];
                s += wv.x * u4.x + wv.y * u4.y + wv.z * u4.z + wv.w * u4.w;
            }
            w2 = 2.f * s;
        }
        float sq = (tid < 256) ? ((it == PITERS) ? vf[tid] * w2 : w2 * w2) : 0.f;
        #pragma unroll
        for (int off = 32; off >= 1; off >>= 1) sq += __shfl_down(sq, off);
        if (tid < 256 && lane == 0) red[tid >> 6] = sq;
        __syncthreads();
        float tot = red[0] + red[1] + red[2] + red[3];
        if (it < PITERS) {
            if (tid < 256) vf[tid] = w2 * (1.f / sqrtf(tot));
        } else if (tid == 0) {
            scal[0] = 1.f / tot;               // invL (Rayleigh quotient)
            scal[1] = LAMBDAV / tot;           // thr
        }
        __syncthreads();
    }

    // ---- phase-1 B fragments (W columns nw*16..+15, K=256) -> registers, forever ----
    bf16x8 wbh[8], wbl[8];
    #pragma unroll
    for (int c = 0; c < 8; ++c) {
        union { unsigned short u[8]; bf16x8 v; } ph, pl;
        #pragma unroll
        for (int tt = 0; tt < 8; ++tt) {
            int j = 32 * c + 8 * l4 + tt;
            float wv = *(const float*)(wst + j * 256 + (((nw * 16 + ln) * 4) ^ ((j & 7) << 4)));
            unsigned short h = f2bf(wv);
            ph.u[tt] = h; pl.u[tt] = f2bf(wv - bf2f(h));
        }
        wbh[c] = ph.v; wbl[c] = pl.v;
    }
    __syncthreads();   // done with fp32 W staging; y region is now free

    // ---- y0 = X0 into LDS (bf16 hi/lo) ----
    #pragma unroll
    for (int t8 = 0; t8 < 8; ++t8)
        #pragma unroll
        for (int r = 0; r < 4; ++r) {
            int row = mt2 * 16 + l4 * 4 + r;
            int cb  = ((ng0 + t8) * 16 + ln) * 2;
            int off = row * 512 + (cb ^ ((row & 7) << 4));
            unsigned short h = f2bf(ym[t8][r]);
            *(unsigned short*)(yhb + off) = h;
            *(unsigned short*)(ylb + off) = f2bf(ym[t8][r] - bf2f(h));
        }
    __syncthreads();

    const float c2  = 2.f * scal[0];
    const float thr = scal[1];
    const int r0row = mw0 * 16 + ln;           // phase-1 A rows (per lane)
    const int r1row = r0row + 16;
    const int x0 = (r0row & 7) << 4, x1 = (r1row & 7) << 4;

    float tt_ = 1.f;
    for (int step = 0; step < NSTEPS; ++step) {
        // ======== phase 1: R = y W - in  (two 16x16 tiles per wave) ========
        f32x4 acc0 = { nin[0][0], nin[0][1], nin[0][2], nin[0][3] };
        f32x4 acc1 = { nin[1][0], nin[1][1], nin[1][2], nin[1][3] };
        #pragma unroll
        for (int c = 0; c < 8; ++c) {
            const int kb = c * 64 + l4 * 16;
            bf16x8 a0h = *(const bf16x8*)(yhb + r0row * 512 + (kb ^ x0));
            bf16x8 a0l = *(const bf16x8*)(ylb + r0row * 512 + (kb ^ x0));
            bf16x8 a1h = *(const bf16x8*)(yhb + r1row * 512 + (kb ^ x1));
            bf16x8 a1l = *(const bf16x8*)(ylb + r1row * 512 + (kb ^ x1));
            acc0 = __builtin_amdgcn_mfma_f32_16x16x32_bf16(a0h, wbh[c], acc0, 0, 0, 0);
            acc0 = __builtin_amdgcn_mfma_f32_16x16x32_bf16(a0l, wbh[c], acc0, 0, 0, 0);
            acc0 = __builtin_amdgcn_mfma_f32_16x16x32_bf16(a0h, wbl[c], acc0, 0, 0, 0);
            acc1 = __builtin_amdgcn_mfma_f32_16x16x32_bf16(a1h, wbh[c], acc1, 0, 0, 0);
            acc1 = __builtin_amdgcn_mfma_f32_16x16x32_bf16(a1l, wbh[c], acc1, 0, 0, 0);
            acc1 = __builtin_amdgcn_mfma_f32_16x16x32_bf16(a1h, wbl[c], acc1, 0, 0, 0);
        }
        #pragma unroll
        for (int s = 0; s < 2; ++s) {
            #pragma unroll
            for (int r = 0; r < 4; ++r) {
                int row = (mw0 + s) * 16 + l4 * 4 + r;
                int off = row * 128 + (((nw * 16 + ln) * 2) ^ ((row & 7) << 4));
                float v = s ? acc1[r] : acc0[r];
                unsigned short h = f2bf(v);
                *(unsigned short*)(rhb + off) = h;
                *(unsigned short*)(rlb + off) = f2bf(v - bf2f(h));
            }
        }
        __syncthreads();

        // ======== phase 2: g = R W^T  (eight 16x16 tiles per wave) ========
        bf16x8 rah[2], ral[2];
        {
            const int arow = mt2 * 16 + ln;
            const int xa = (arow & 7) << 4;
            #pragma unroll
            for (int c = 0; c < 2; ++c) {
                const int kb = c * 64 + l4 * 16;
                rah[c] = *(const bf16x8*)(rhb + arow * 128 + (kb ^ xa));
                ral[c] = *(const bf16x8*)(rlb + arow * 128 + (kb ^ xa));
            }
        }
        f32x4 g[8];
        #pragma unroll
        for (int t8 = 0; t8 < 8; ++t8) {
            g[t8] = (f32x4){0.f, 0.f, 0.f, 0.f};
            const int jrow = (ng0 + t8) * 16 + ln;
            const int xb = (jrow & 7) << 4;
            #pragma unroll
            for (int c = 0; c < 2; ++c) {
                const int kb = c * 64 + l4 * 16;
                bf16x8 bh = *(const bf16x8*)(whb + jrow * 128 + (kb ^ xb));
                bf16x8 bl = *(const bf16x8*)(wlb + jrow * 128 + (kb ^ xb));
                g[t8] = __builtin_amdgcn_mfma_f32_16x16x32_bf16(rah[c], bh, g[t8], 0, 0, 0);
                g[t8] = __builtin_amdgcn_mfma_f32_16x16x32_bf16(ral[c], bh, g[t8], 0, 0, 0);
                g[t8] = __builtin_amdgcn_mfma_f32_16x16x32_bf16(rah[c], bl, g[t8], 0, 0, 0);
            }
        }

        // ======== update: prox + momentum, write y back ========
        const float t2v = 0.5f + 0.5f * sqrtf(1.f + 4.f * tt_ * tt_);
        const float mom = (tt_ - 1.f) / t2v;
        tt_ = t2v;
        #pragma unroll
        for (int t8 = 0; t8 < 8; ++t8) {
            #pragma unroll
            for (int r = 0; r < 4; ++r) {
                float u  = ym[t8][r] - c2 * g[t8][r];
                float x2 = fmaxf(u - thr, 0.f) + fminf(u + thr, 0.f);
                float yn = x2 + mom * (x2 - xm[t8][r]);
                xm[t8][r] = x2; ym[t8][r] = yn;
                int row = mt2 * 16 + l4 * 4 + r;
                int cb  = ((ng0 + t8) * 16 + ln) * 2;
                int off = row * 512 + (cb ^ ((row & 7) << 4));
                unsigned short h = f2bf(yn);
                *(unsigned short*)(yhb + off) = h;
                *(unsigned short*)(ylb + off) = f2bf(yn - bf2f(h));
            }
        }
        __syncthreads();
    }

    // ---- store X ----
    #pragma unroll
    for (int t8 = 0; t8 < 8; ++t8)
        #pragma unroll
        for (int r = 0; r < 4; ++r)
            out[(size_t)(rb + mt2 * 16 + l4 * 4 + r) * DOUT + (ng0 + t8) * 16 + ln] = xm[t8][r];
}

extern "C" void kernel_launch(void* const* d_in, const int* in_sizes, int n_in,
                              void* d_out, int out_size, void* d_ws, size_t ws_size,
                              hipStream_t stream) {
    (void)in_sizes; (void)n_in; (void)d_ws; (void)ws_size; (void)out_size;
    const float* inp = (const float*)d_in[0];   // [16384, 64]
    const float* Wg  = (const float*)d_in[1];   // [256, 64]
    const float* X0  = (const float*)d_in[2];   // [16384, 256]
    float* outp      = (float*)d_out;           // [16384, 256]
    fista_mfma<<<16384 / RPB, NTH, 0, stream>>>(inp, Wg, X0, outp);
}